// Round 9
// baseline (270.163 us; speedup 1.0000x reference)
//
#include <hip/hip_runtime.h>

// ---- hash / bucket constants ----
#define HBITS 19
#define HSIZE (1u << HBITS)
#define HMASK (HSIZE - 1u)
#define EMPTY_KEY 0xFFFFFFFFu
#define SLOTS 8   // direct slots per voxel; overflow (P~1e-4) goes to chain

__device__ __forceinline__ unsigned hash_key(unsigned k) {
    return (k * 2654435761u) >> (32 - HBITS);
}

__device__ __forceinline__ unsigned pack_key(int4 c) {
    // c.x = batch (<4), c.y/z/w = xyz in [0,256)
    return ((unsigned)c.x << 24) | ((unsigned)c.y << 16) |
           ((unsigned)c.z << 8) | (unsigned)c.w;
}

// Kernel A: insert voxel keys; htab[h] = (key, min original index).
__global__ __launch_bounds__(256)
void build_hash(const int4* __restrict__ tgt_coords, int M,
                uint2* __restrict__ htab) {
    int v = blockIdx.x * blockDim.x + threadIdx.x;
    if (v >= M) return;
    unsigned key = pack_key(tgt_coords[v]);
    unsigned h = hash_key(key);
    while (true) {
        unsigned prev = atomicCAS(&htab[h].x, EMPTY_KEY, key);
        if (prev == EMPTY_KEY || prev == key) {
            atomicMin(&htab[h].y, (unsigned)v);   // canonical = min index
            break;
        }
        h = (h + 1u) & HMASK;
    }
}

// Kernel A2: resolve canonical voxel index once per voxel.
__global__ __launch_bounds__(256)
void canonize(const int4* __restrict__ tgt_coords,
              const uint2* __restrict__ htab, int M,
              int* __restrict__ canon) {
    int v = blockIdx.x * blockDim.x + threadIdx.x;
    if (v >= M) return;
    unsigned key = pack_key(tgt_coords[v]);
    unsigned h = hash_key(key);
    uint2 e = htab[h];
    while (e.x != key) { h = (h + 1u) & HMASK; e = htab[h]; }
    canon[v] = (int)e.y;
}

// Kernel B: each point claims a bucket slot in its canonical voxel.
__global__ __launch_bounds__(256)
void fill_slots(const int* __restrict__ pts_idx,
                const int* __restrict__ canon,
                int BN,
                int* __restrict__ cnt,      // (M) init -1
                int* __restrict__ slotbuf,  // (M*SLOTS) no init needed
                int* __restrict__ ohead,    // (M) init -1
                int* __restrict__ nxt) {    // (BN) no init needed
    int p = blockIdx.x * blockDim.x + threadIdx.x;
    if (p >= BN) return;
    int c = canon[pts_idx[p]];
    int idx = atomicAdd(&cnt[c], 1) + 1;
    if (idx < SLOTS) slotbuf[c * SLOTS + idx] = p;
    else             nxt[p] = atomicExch(&ohead[c], p);   // rare
}

// Kernel E v8: FUSED gather-mean + 96->32 GEMV, 2-deep pipeline (r7's
// proven best) + MAX OCCUPANCY.
// Round-8 post-mortem: 4-deep regressed (75->88us, occ 44->38) — depth
// is exhausted. The remaining lever is WAVES: a latency-bound random
// gather scales with total outstanding requests/CU = waves x depth.
// r1 (3.5KB LDS, 82% occ) showed the same gather running ~as fast as
// our best pipelined version at 44% occ. v8 removes the LDS occupancy
// cap by NOT staging tgt through LDS: phase 2 reads tgt_feats rows
// directly from global (coalesced float4/thread — r0's matmul_scalar
// pattern, same FMA order -> bitwise-identical output). LDS shrinks to
// mean-only [64][66] + metadata = 19.2KB -> 8 blocks/CU -> 32 waves
// (was 5 blocks/20 waves). VGPR 44-52 <= 64 keeps 8 waves/SIMD legal;
// __launch_bounds__(256,8) makes the cap explicit.
#define VOXB 64
#define MSTR 66   // mean row stride (even -> float2-aligned; bank str 2)
#define NPASS (VOXB / 8)

struct PassRegs {
    float2 f0, f1, f2, f3, f4, f5, f6, f7;
    int n;
    int vb;
};

__device__ __forceinline__ void issue_pass(
    PassRegs& r, int pp, int grp, int g,
    const float2* __restrict__ pf2,
    const int* scnt, const int4* sslot) {
    int vb = pp * 8 + grp;
    r.vb = vb;
    int n = scnt[vb] + 1;        // v>=M staged as cnt=-1 -> n=0 (all masked)
    r.n = n;
    int4 sa = sslot[vb * 2];
    int4 sb = sslot[vb * 2 + 1];
    int p0 = (n > 0) ? sa.x : 0;
    int p1 = (n > 1) ? sa.y : 0;
    int p2 = (n > 2) ? sa.z : 0;
    int p3 = (n > 3) ? sa.w : 0;
    int p4 = (n > 4) ? sb.x : 0;
    int p5 = (n > 5) ? sb.y : 0;
    int p6 = (n > 6) ? sb.z : 0;
    int p7 = (n > 7) ? sb.w : 0;
    // 8 independent row loads, issued back-to-back
    r.f0 = pf2[(size_t)p0 * 32 + g];
    r.f1 = pf2[(size_t)p1 * 32 + g];
    r.f2 = pf2[(size_t)p2 * 32 + g];
    r.f3 = pf2[(size_t)p3 * 32 + g];
    r.f4 = pf2[(size_t)p4 * 32 + g];
    r.f5 = pf2[(size_t)p5 * 32 + g];
    r.f6 = pf2[(size_t)p6 * 32 + g];
    r.f7 = pf2[(size_t)p7 * 32 + g];
}

__device__ __forceinline__ void consume_pass(
    const PassRegs& r, int g, int vbase, int M,
    const float2* __restrict__ pf2,
    const int* __restrict__ ohead, const int* __restrict__ nxt,
    float (*ms)[MSTR]) {
    int v = vbase + r.vb;
    if (v >= M) return;
    int n = r.n;
    float m0 = (n > 0) ? 1.f : 0.f;
    float m1 = (n > 1) ? 1.f : 0.f;
    float m2 = (n > 2) ? 1.f : 0.f;
    float m3 = (n > 3) ? 1.f : 0.f;
    float m4 = (n > 4) ? 1.f : 0.f;
    float m5 = (n > 5) ? 1.f : 0.f;
    float m6 = (n > 6) ? 1.f : 0.f;
    float m7 = (n > 7) ? 1.f : 0.f;
    float sx = ((r.f0.x * m0 + r.f1.x * m1) + (r.f2.x * m2 + r.f3.x * m3)) +
               ((r.f4.x * m4 + r.f5.x * m5) + (r.f6.x * m6 + r.f7.x * m7));
    float sy = ((r.f0.y * m0 + r.f1.y * m1) + (r.f2.y * m2 + r.f3.y * m3)) +
               ((r.f4.y * m4 + r.f5.y * m5) + (r.f6.y * m6 + r.f7.y * m7));
    if (n > SLOTS) {   // extremely rare overflow chain
        int p = ohead[v];
        while (p >= 0) {
            float2 f = pf2[(size_t)p * 32 + g];
            sx += f.x; sy += f.y;
            p = nxt[p];
        }
    }
    float inv = 1.0f / fmaxf((float)n, 1.0f);
    *reinterpret_cast<float2*>(&ms[r.vb][2 * g]) =
        make_float2(sx * inv, sy * inv);         // mean channels 2g,2g+1
}

__global__ __launch_bounds__(256, 8)
void gather_fuse(const float2* __restrict__ pf2,   // (BN,64) as (BN,32) float2
                 const float* __restrict__ tgtf,   // (M,32)
                 const int* __restrict__ cnt,
                 const int4* __restrict__ slot4,   // slotbuf as (M,2) int4
                 const int* __restrict__ ohead,
                 const int* __restrict__ nxt,
                 const float* __restrict__ W,      // (96,32)
                 const float* __restrict__ bias,   // (32,)
                 int M,
                 float* __restrict__ out) {        // (M,32)
    __shared__ __align__(16) float ms[VOXB][MSTR];   // 16896 B (mean only)
    __shared__ int scnt[VOXB];                       // 256 B
    __shared__ __align__(16) int4 sslot[VOXB * 2];   // 2048 B
    // total ~19.2 KB -> 8 blocks/CU; 256 thr -> 32 waves/CU (wave-limit max)

    int t = threadIdx.x;
    int vbase = blockIdx.x * VOXB;

    // ---- pre-phase: coalesced slot-metadata staging ----
    if (t < VOXB) {
        int v = vbase + t;
        scnt[t] = (v < M) ? cnt[v] : -1;
    }
    if (t < VOXB * 2) {
        int j = vbase * 2 + t;
        sslot[t] = (j < M * 2) ? slot4[j] : make_int4(0, 0, 0, 0);
    }
    __syncthreads();

    int grp = t >> 5;
    int g   = t & 31;

    // ---- phase 1: 2-deep register-pipelined gather (r7's proven best) ----
    {
        PassRegs A, B;
        issue_pass(A, 0, grp, g, pf2, scnt, sslot);
#pragma unroll
        for (int pp = 0; pp < NPASS; pp += 2) {
            if (pp + 1 < NPASS)
                issue_pass(B, pp + 1, grp, g, pf2, scnt, sslot);
            consume_pass(A, g, vbase, M, pf2, ohead, nxt, ms);
            if (pp + 2 < NPASS)
                issue_pass(A, pp + 2, grp, g, pf2, scnt, sslot);
            if (pp + 1 < NPASS)
                consume_pass(B, g, vbase, M, pf2, ohead, nxt, ms);
        }
    }

    __syncthreads();

    // ---- phase 2: GEMV, lane = voxel, wave = 8-channel block (scalar W).
    // tgt comes straight from global (coalesced float4/thread, r0 pattern);
    // mean from LDS. FMA order identical to all prior rounds.
    int vb2 = t & (VOXB - 1);
    int ocb = __builtin_amdgcn_readfirstlane((t >> 6) << 3);  // 0/8/16/24
    int v2  = vbase + vb2;
    if (v2 < M) {
        float acc[8];
#pragma unroll
        for (int j = 0; j < 8; ++j) acc[j] = bias[ocb + j];

        // k = 0..31: tgt region, direct global float4 reads
        const float4* tr = reinterpret_cast<const float4*>(tgtf + (size_t)v2 * 32);
#pragma unroll
        for (int k4 = 0; k4 < 8; ++k4) {
            float4 x = tr[k4];
            const float* w0 = W + (k4 * 4 + 0) * 32 + ocb;
            const float* w1 = W + (k4 * 4 + 1) * 32 + ocb;
            const float* w2 = W + (k4 * 4 + 2) * 32 + ocb;
            const float* w3 = W + (k4 * 4 + 3) * 32 + ocb;
#pragma unroll
            for (int j = 0; j < 8; ++j) {
                acc[j] = fmaf(x.x, w0[j], acc[j]);
                acc[j] = fmaf(x.y, w1[j], acc[j]);
                acc[j] = fmaf(x.z, w2[j], acc[j]);
                acc[j] = fmaf(x.w, w3[j], acc[j]);
            }
        }
        // k = 32..95: mean region from LDS (float2 pairs, 8B-aligned)
#pragma unroll
        for (int k4 = 0; k4 < 16; ++k4) {
            float2 xa = *reinterpret_cast<const float2*>(&ms[vb2][k4 * 4]);
            float2 xb = *reinterpret_cast<const float2*>(&ms[vb2][k4 * 4 + 2]);
            const float* w0 = W + ((k4 + 8) * 4 + 0) * 32 + ocb;
            const float* w1 = W + ((k4 + 8) * 4 + 1) * 32 + ocb;
            const float* w2 = W + ((k4 + 8) * 4 + 2) * 32 + ocb;
            const float* w3 = W + ((k4 + 8) * 4 + 3) * 32 + ocb;
#pragma unroll
            for (int j = 0; j < 8; ++j) {
                acc[j] = fmaf(xa.x, w0[j], acc[j]);
                acc[j] = fmaf(xa.y, w1[j], acc[j]);
                acc[j] = fmaf(xb.x, w2[j], acc[j]);
                acc[j] = fmaf(xb.y, w3[j], acc[j]);
            }
        }

        float4* o = reinterpret_cast<float4*>(out + (size_t)v2 * 32 + ocb);
        o[0] = make_float4(acc[0], acc[1], acc[2], acc[3]);
        o[1] = make_float4(acc[4], acc[5], acc[6], acc[7]);
    }
}

extern "C" void kernel_launch(void* const* d_in, const int* in_sizes, int n_in,
                              void* d_out, int out_size, void* d_ws, size_t ws_size,
                              hipStream_t stream) {
    const float* pfeat      = (const float*)d_in[0];  // (BN,64)
    const float* tgt_feats  = (const float*)d_in[1];  // (M,32)
    const float* W_fuse     = (const float*)d_in[2];  // (96,32)
    const float* b_fuse     = (const float*)d_in[3];  // (32,)
    const int*   tgt_coords = (const int*)d_in[4];    // (M,4)
    const int*   pts_idx    = (const int*)d_in[5];    // (BN,)
    float* out = (float*)d_out;                       // (M,32)

    const int M  = in_sizes[4] / 4;
    const int BN = in_sizes[5];

    // workspace: [htab 4MB | cnt M | ohead M]  <- single 0xFF memset region
    //            [canon M | slotbuf M*8 | nxt BN] <- write-before-read
    char* ws = (char*)d_ws;
    uint2* htab    = (uint2*)ws;
    size_t off = (size_t)HSIZE * 8;
    int*   cnt     = (int*)(ws + off);              off += (size_t)M * 4;
    int*   ohead   = (int*)(ws + off);              off += (size_t)M * 4;
    int*   canon   = (int*)(ws + off);              off += (size_t)M * 4;
    int*   slotbuf = (int*)(ws + off);              off += (size_t)M * SLOTS * 4;
    int*   nxt     = (int*)(ws + off);

    size_t ff_bytes = (size_t)HSIZE * 8 + (size_t)M * 8;  // htab + cnt + ohead
    hipMemsetAsync(htab, 0xFF, ff_bytes, stream);  // EMPTY_KEY / UINT_MAX / -1

    const int TB = 256;
    build_hash<<<(M + TB - 1) / TB, TB, 0, stream>>>(
        (const int4*)tgt_coords, M, htab);
    canonize<<<(M + TB - 1) / TB, TB, 0, stream>>>(
        (const int4*)tgt_coords, htab, M, canon);
    fill_slots<<<(BN + TB - 1) / TB, TB, 0, stream>>>(
        pts_idx, canon, BN, cnt, slotbuf, ohead, nxt);
    gather_fuse<<<(M + VOXB - 1) / VOXB, TB, 0, stream>>>(
        (const float2*)pfeat, tgt_feats, cnt, (const int4*)slotbuf, ohead, nxt,
        W_fuse, b_fuse, M, out);
}

// Round 10
// 258.976 us; speedup vs baseline: 1.0432x; 1.0432x over previous
//
#include <hip/hip_runtime.h>

// ---- hash / bucket constants ----
#define HBITS 19
#define HSIZE (1u << HBITS)
#define HMASK (HSIZE - 1u)
#define EMPTY_KEY 0xFFFFFFFFu
#define SLOTS 4   // direct slots per voxel; overflow (P~5% at avg n=2) chains

__device__ __forceinline__ unsigned hash_key(unsigned k) {
    return (k * 2654435761u) >> (32 - HBITS);
}

__device__ __forceinline__ unsigned pack_key(int4 c) {
    // c.x = batch (<4), c.y/z/w = xyz in [0,256)
    return ((unsigned)c.x << 24) | ((unsigned)c.y << 16) |
           ((unsigned)c.z << 8) | (unsigned)c.w;
}

// Kernel A: insert voxel keys; htab[h] = (key, min original index).
__global__ __launch_bounds__(256)
void build_hash(const int4* __restrict__ tgt_coords, int M,
                uint2* __restrict__ htab) {
    int v = blockIdx.x * blockDim.x + threadIdx.x;
    if (v >= M) return;
    unsigned key = pack_key(tgt_coords[v]);
    unsigned h = hash_key(key);
    while (true) {
        unsigned prev = atomicCAS(&htab[h].x, EMPTY_KEY, key);
        if (prev == EMPTY_KEY || prev == key) {
            atomicMin(&htab[h].y, (unsigned)v);   // canonical = min index
            break;
        }
        h = (h + 1u) & HMASK;
    }
}

// Kernel A2: resolve canonical voxel index once per voxel.
__global__ __launch_bounds__(256)
void canonize(const int4* __restrict__ tgt_coords,
              const uint2* __restrict__ htab, int M,
              int* __restrict__ canon) {
    int v = blockIdx.x * blockDim.x + threadIdx.x;
    if (v >= M) return;
    unsigned key = pack_key(tgt_coords[v]);
    unsigned h = hash_key(key);
    uint2 e = htab[h];
    while (e.x != key) { h = (h + 1u) & HMASK; e = htab[h]; }
    canon[v] = (int)e.y;
}

// Kernel B: each point claims a bucket slot in its canonical voxel.
__global__ __launch_bounds__(256)
void fill_slots(const int* __restrict__ pts_idx,
                const int* __restrict__ canon,
                int BN,
                int* __restrict__ cnt,      // (M) init -1
                int* __restrict__ slotbuf,  // (M*SLOTS) no init needed
                int* __restrict__ ohead,    // (M) init -1
                int* __restrict__ nxt) {    // (BN) no init needed
    int p = blockIdx.x * blockDim.x + threadIdx.x;
    if (p >= BN) return;
    int c = canon[pts_idx[p]];
    int idx = atomicAdd(&cnt[c], 1) + 1;
    if (idx < SLOTS) slotbuf[c * SLOTS + idx] = p;
    else             nxt[p] = atomicExch(&ohead[c], p);   // ~5% at SLOTS=4
}

// Kernel E v9: FUSED gather-mean + 96->32 GEMV.
// Round-9 ledger insight: FETCH flat at 66MB across r5-r9 while ISSUED
// load volume was 409.6MB — avg n = BN/M = 2, so 8 masked slot-loads
// per voxel = 75% dummy row-0 requests. Dummies are cache-absorbed but
// consume VMEM issue slots / vmcnt queue / L1-L2 request BW (~5.5TB/s
// logical = suspected request-path ceiling). v9 halves requests:
//  - SLOTS=4 (n>4, ~5% of voxels, uses the existing overflow chain)
//  - each group handles 2 voxels/pass (2x4 = 8 loads/pass) -> EXACT r7
//    pipeline shape (8 loads/pass, 2-deep A/B, ~16 float2 in flight)
//    with half the total requests and 4 passes instead of 8.
//  - r9's LDS diet kept (no tgt staging; phase 2 reads tgt from global,
//    r0 pattern): ms+scnt+sslot ~= 18.2KB -> 8 blocks/CU.
//  - NO launch_bounds min-waves hint (r9 proved it forces VGPR 32 and
//    kills the pipeline).
// Confirmation signals: VGPR 44-56 (pipeline alive), occ 55-70%.
// Pre-commit: >=68us at those signals = request wall is structural.
#define VOXB 64
#define MSTR 66   // mean row stride (even -> float2-aligned; bank str 2)
#define NPASS (VOXB / 16)   // 8 groups x 2 voxels/pass = 16 voxels/pass

struct PassRegs {
    float2 fa0, fa1, fa2, fa3;   // voxel a slots
    float2 fb0, fb1, fb2, fb3;   // voxel b slots
    int na, nb;
    int vba;                     // voxel b = vba+1
};

__device__ __forceinline__ void issue_pass(
    PassRegs& r, int pp, int grp, int g,
    const float2* __restrict__ pf2,
    const int* scnt, const int4* sslot) {
    int vba = pp * 16 + grp * 2;
    r.vba = vba;
    int na = scnt[vba] + 1;      // v>=M staged as cnt=-1 -> n=0 (all masked)
    int nb = scnt[vba + 1] + 1;
    r.na = na; r.nb = nb;
    int4 sa = sslot[vba];
    int4 sb = sslot[vba + 1];
    int pa0 = (na > 0) ? sa.x : 0;
    int pa1 = (na > 1) ? sa.y : 0;
    int pa2 = (na > 2) ? sa.z : 0;
    int pa3 = (na > 3) ? sa.w : 0;
    int pb0 = (nb > 0) ? sb.x : 0;
    int pb1 = (nb > 1) ? sb.y : 0;
    int pb2 = (nb > 2) ? sb.z : 0;
    int pb3 = (nb > 3) ? sb.w : 0;
    // 8 independent row loads, issued back-to-back
    r.fa0 = pf2[(size_t)pa0 * 32 + g];
    r.fa1 = pf2[(size_t)pa1 * 32 + g];
    r.fa2 = pf2[(size_t)pa2 * 32 + g];
    r.fa3 = pf2[(size_t)pa3 * 32 + g];
    r.fb0 = pf2[(size_t)pb0 * 32 + g];
    r.fb1 = pf2[(size_t)pb1 * 32 + g];
    r.fb2 = pf2[(size_t)pb2 * 32 + g];
    r.fb3 = pf2[(size_t)pb3 * 32 + g];
}

__device__ __forceinline__ void sum_voxel(
    float2 f0, float2 f1, float2 f2, float2 f3, int n, int v, int vb, int g,
    const float2* __restrict__ pf2,
    const int* __restrict__ ohead, const int* __restrict__ nxt,
    float (*ms)[MSTR]) {
    float m0 = (n > 0) ? 1.f : 0.f;
    float m1 = (n > 1) ? 1.f : 0.f;
    float m2 = (n > 2) ? 1.f : 0.f;
    float m3 = (n > 3) ? 1.f : 0.f;
    float sx = (f0.x * m0 + f1.x * m1) + (f2.x * m2 + f3.x * m3);
    float sy = (f0.y * m0 + f1.y * m1) + (f2.y * m2 + f3.y * m3);
    if (n > SLOTS) {   // ~5% of voxels: walk overflow chain
        int p = ohead[v];
        while (p >= 0) {
            float2 f = pf2[(size_t)p * 32 + g];
            sx += f.x; sy += f.y;
            p = nxt[p];
        }
    }
    float inv = 1.0f / fmaxf((float)n, 1.0f);
    *reinterpret_cast<float2*>(&ms[vb][2 * g]) =
        make_float2(sx * inv, sy * inv);         // mean channels 2g,2g+1
}

__device__ __forceinline__ void consume_pass(
    const PassRegs& r, int g, int vbase, int M,
    const float2* __restrict__ pf2,
    const int* __restrict__ ohead, const int* __restrict__ nxt,
    float (*ms)[MSTR]) {
    int va = vbase + r.vba;
    if (va < M)
        sum_voxel(r.fa0, r.fa1, r.fa2, r.fa3, r.na, va, r.vba, g,
                  pf2, ohead, nxt, ms);
    int vb = va + 1;
    if (vb < M)
        sum_voxel(r.fb0, r.fb1, r.fb2, r.fb3, r.nb, vb, r.vba + 1, g,
                  pf2, ohead, nxt, ms);
}

__global__ __launch_bounds__(256)
void gather_fuse(const float2* __restrict__ pf2,   // (BN,64) as (BN,32) float2
                 const float* __restrict__ tgtf,   // (M,32)
                 const int* __restrict__ cnt,
                 const int4* __restrict__ slot4,   // slotbuf as (M) int4
                 const int* __restrict__ ohead,
                 const int* __restrict__ nxt,
                 const float* __restrict__ W,      // (96,32)
                 const float* __restrict__ bias,   // (32,)
                 int M,
                 float* __restrict__ out) {        // (M,32)
    __shared__ __align__(16) float ms[VOXB][MSTR];   // 16896 B (mean only)
    __shared__ int scnt[VOXB];                       // 256 B
    __shared__ __align__(16) int4 sslot[VOXB];       // 1024 B
    // total ~18.2 KB -> 8 blocks/CU

    int t = threadIdx.x;
    int vbase = blockIdx.x * VOXB;

    // ---- pre-phase: coalesced slot-metadata staging ----
    if (t < VOXB) {
        int v = vbase + t;
        scnt[t]  = (v < M) ? cnt[v] : -1;
        sslot[t] = (v < M) ? slot4[v] : make_int4(0, 0, 0, 0);
    }
    __syncthreads();

    int grp = t >> 5;
    int g   = t & 31;

    // ---- phase 1: 2-deep register-pipelined gather, 2 voxels/group/pass ----
    {
        PassRegs A, B;
        issue_pass(A, 0, grp, g, pf2, scnt, sslot);
#pragma unroll
        for (int pp = 0; pp < NPASS; pp += 2) {
            if (pp + 1 < NPASS)
                issue_pass(B, pp + 1, grp, g, pf2, scnt, sslot);
            consume_pass(A, g, vbase, M, pf2, ohead, nxt, ms);
            if (pp + 2 < NPASS)
                issue_pass(A, pp + 2, grp, g, pf2, scnt, sslot);
            if (pp + 1 < NPASS)
                consume_pass(B, g, vbase, M, pf2, ohead, nxt, ms);
        }
    }

    __syncthreads();

    // ---- phase 2: GEMV, lane = voxel, wave = 8-channel block (scalar W).
    // tgt straight from global (coalesced float4/thread); mean from LDS.
    int vb2 = t & (VOXB - 1);
    int ocb = __builtin_amdgcn_readfirstlane((t >> 6) << 3);  // 0/8/16/24
    int v2  = vbase + vb2;
    if (v2 < M) {
        float acc[8];
#pragma unroll
        for (int j = 0; j < 8; ++j) acc[j] = bias[ocb + j];

        // k = 0..31: tgt region, direct global float4 reads
        const float4* tr = reinterpret_cast<const float4*>(tgtf + (size_t)v2 * 32);
#pragma unroll
        for (int k4 = 0; k4 < 8; ++k4) {
            float4 x = tr[k4];
            const float* w0 = W + (k4 * 4 + 0) * 32 + ocb;
            const float* w1 = W + (k4 * 4 + 1) * 32 + ocb;
            const float* w2 = W + (k4 * 4 + 2) * 32 + ocb;
            const float* w3 = W + (k4 * 4 + 3) * 32 + ocb;
#pragma unroll
            for (int j = 0; j < 8; ++j) {
                acc[j] = fmaf(x.x, w0[j], acc[j]);
                acc[j] = fmaf(x.y, w1[j], acc[j]);
                acc[j] = fmaf(x.z, w2[j], acc[j]);
                acc[j] = fmaf(x.w, w3[j], acc[j]);
            }
        }
        // k = 32..95: mean region from LDS (float2 pairs, 8B-aligned)
#pragma unroll
        for (int k4 = 0; k4 < 16; ++k4) {
            float2 xa = *reinterpret_cast<const float2*>(&ms[vb2][k4 * 4]);
            float2 xb = *reinterpret_cast<const float2*>(&ms[vb2][k4 * 4 + 2]);
            const float* w0 = W + ((k4 + 8) * 4 + 0) * 32 + ocb;
            const float* w1 = W + ((k4 + 8) * 4 + 1) * 32 + ocb;
            const float* w2 = W + ((k4 + 8) * 4 + 2) * 32 + ocb;
            const float* w3 = W + ((k4 + 8) * 4 + 3) * 32 + ocb;
#pragma unroll
            for (int j = 0; j < 8; ++j) {
                acc[j] = fmaf(xa.x, w0[j], acc[j]);
                acc[j] = fmaf(xa.y, w1[j], acc[j]);
                acc[j] = fmaf(xb.x, w2[j], acc[j]);
                acc[j] = fmaf(xb.y, w3[j], acc[j]);
            }
        }

        float4* o = reinterpret_cast<float4*>(out + (size_t)v2 * 32 + ocb);
        o[0] = make_float4(acc[0], acc[1], acc[2], acc[3]);
        o[1] = make_float4(acc[4], acc[5], acc[6], acc[7]);
    }
}

extern "C" void kernel_launch(void* const* d_in, const int* in_sizes, int n_in,
                              void* d_out, int out_size, void* d_ws, size_t ws_size,
                              hipStream_t stream) {
    const float* pfeat      = (const float*)d_in[0];  // (BN,64)
    const float* tgt_feats  = (const float*)d_in[1];  // (M,32)
    const float* W_fuse     = (const float*)d_in[2];  // (96,32)
    const float* b_fuse     = (const float*)d_in[3];  // (32,)
    const int*   tgt_coords = (const int*)d_in[4];    // (M,4)
    const int*   pts_idx    = (const int*)d_in[5];    // (BN,)
    float* out = (float*)d_out;                       // (M,32)

    const int M  = in_sizes[4] / 4;
    const int BN = in_sizes[5];

    // workspace: [htab 4MB | cnt M | ohead M]  <- single 0xFF memset region
    //            [canon M | slotbuf M*4 | nxt BN] <- write-before-read
    char* ws = (char*)d_ws;
    uint2* htab    = (uint2*)ws;
    size_t off = (size_t)HSIZE * 8;
    int*   cnt     = (int*)(ws + off);              off += (size_t)M * 4;
    int*   ohead   = (int*)(ws + off);              off += (size_t)M * 4;
    int*   canon   = (int*)(ws + off);              off += (size_t)M * 4;
    int*   slotbuf = (int*)(ws + off);              off += (size_t)M * SLOTS * 4;
    int*   nxt     = (int*)(ws + off);

    size_t ff_bytes = (size_t)HSIZE * 8 + (size_t)M * 8;  // htab + cnt + ohead
    hipMemsetAsync(htab, 0xFF, ff_bytes, stream);  // EMPTY_KEY / UINT_MAX / -1

    const int TB = 256;
    build_hash<<<(M + TB - 1) / TB, TB, 0, stream>>>(
        (const int4*)tgt_coords, M, htab);
    canonize<<<(M + TB - 1) / TB, TB, 0, stream>>>(
        (const int4*)tgt_coords, htab, M, canon);
    fill_slots<<<(BN + TB - 1) / TB, TB, 0, stream>>>(
        pts_idx, canon, BN, cnt, slotbuf, ohead, nxt);
    gather_fuse<<<(M + VOXB - 1) / VOXB, TB, 0, stream>>>(
        (const float2*)pfeat, tgt_feats, cnt, (const int4*)slotbuf, ohead, nxt,
        W_fuse, b_fuse, M, out);
}